// Round 12
// baseline (213.523 us; speedup 1.0000x reference)
//
#include <hip/hip_runtime.h>
#include <hip/hip_cooperative_groups.h>

namespace cg = cooperative_groups;

typedef unsigned int u32;
typedef unsigned long long u64;
typedef unsigned short u16;

#define BATCH 32
#define NPRI  200000
#define TOPK  200
#define CAP   4096
#define PRE_BITS 0x3F7F8000u   // 0.998046875f; expected ~391 captures/img
#define NROLE 8                // blocks per image
#define SEGCAP 256             // slots per (img, role); ~49 expected, 30 sigma margin
#define NSLICE 4

// LDS map (48 KB static, aliased across stages)
#define OFF_LKEYS 0            // u64[4096]  (stage A lbuf aliases; fb hist aliases)
#define OFF_SKEYS 32768        // u64[512]   (fb csum aliases)
#define OFF_HIST  36864        // u32[512]
#define OFF_CNT2  38912        // u32[512]
#define OFF_SUFF  40960        // u32[512]
#define OFF_SBOX  43008        // float4[200]
#define OFF_SAREA 46208        // float[200]
#define OFF_SSC   47008        // float[200]
#define SMEM_BYTES 47808

__device__ __forceinline__ u32 binOf(u64 key) {
  u32 bits = (u32)(key >> 32);
  if (bits < PRE_BITS) return 0u;
  u32 b = (bits - PRE_BITS) >> 6;
  return b > 511u ? 511u : b;
}

__global__ __launch_bounds__(1024) void k_fused(
    const float* __restrict__ loc, const float* __restrict__ priors,
    const float* __restrict__ conf,
    u32* __restrict__ cntA, u32* __restrict__ cnt1A, u64* __restrict__ cand,
    u16* __restrict__ gmask16, float* __restrict__ out)
{
  __shared__ __align__(16) char smem[SMEM_BYTES];
  __shared__ u32 pre[NROLE], ln[NROLE];
  __shared__ u64 sact[4];
  __shared__ u32 s_lcnt, s_lc1, s_nc, s_c1, s_flag, s_T, s_ctr;

  u64*    lkeys  = (u64*)(smem + OFF_LKEYS);
  u64*    skeys  = (u64*)(smem + OFF_SKEYS);
  u32*    hist   = (u32*)(smem + OFF_HIST);
  u32*    cnt2   = (u32*)(smem + OFF_CNT2);
  u32*    suffst = (u32*)(smem + OFF_SUFF);
  float4* sbox   = (float4*)(smem + OFF_SBOX);
  float*  sarea  = (float*)(smem + OFF_SAREA);
  float*  sscore = (float*)(smem + OFF_SSC);

  cg::grid_group grid = cg::this_grid();
  const int img  = blockIdx.x >> 3;
  const int role = blockIdx.x & 7;
  const int tid  = threadIdx.x;
  float* oimg = out + (size_t)img * (2*TOPK*5);

  // ================= stage A: capture + zero slab =================
  {
    if (tid == 0) { s_lcnt = 0u; s_lc1 = 0u; }
    if (tid < 250) oimg[role*250 + tid] = 0.0f;
    __syncthreads();
    u64* lbuf = lkeys;                 // first SEGCAP entries
    const float4* cp = ((const float4*)conf) + (size_t)img * (NPRI/2);
    u64* cd = cand + ((size_t)img*NROLE + role) * SEGCAP;
    u32 my1 = 0;
    for (int i = role*1024 + tid; i < NPRI/2; i += NROLE*1024) {
      float4 v = cp[i];
      if (v.y > 0.01f) {
        ++my1; u32 bits = __float_as_uint(v.y);
        if (bits >= PRE_BITS) {
          u32 p = atomicAdd(&s_lcnt, 1u);
          if (p < SEGCAP) lbuf[p] = ((u64)bits << 32) | (u64)(0xFFFFFFFFu - (u32)(2*i));
        }
      }
      if (v.w > 0.01f) {
        ++my1; u32 bits = __float_as_uint(v.w);
        if (bits >= PRE_BITS) {
          u32 p = atomicAdd(&s_lcnt, 1u);
          if (p < SEGCAP) lbuf[p] = ((u64)bits << 32) | (u64)(0xFFFFFFFFu - (u32)(2*i+1));
        }
      }
    }
    if (my1) atomicAdd(&s_lc1, my1);
    __syncthreads();
    u32 n = s_lcnt, nn = (n > SEGCAP) ? SEGCAP : n;
    for (u32 t = tid; t < nn; t += 1024) cd[t] = lbuf[t];
    if (tid == 0) {
      cntA[img*NROLE + role]  = (n > SEGCAP) ? (SEGCAP | 0x80000000u) : n;
      cnt1A[img*NROLE + role] = s_lc1;
    }
  }
  __threadfence();
  grid.sync();

  // ================= stage B: gather + sort + decode + IoU slice =================
  {
    if (tid < 512) { hist[tid] = 0u; cnt2[tid] = 0u; skeys[tid] = 0ull; }
    if (tid == 0) { s_T = 0u; s_ctr = 0u; }
    if (tid < 64) {
      u32 v  = (tid < 8) ? cntA[img*NROLE + tid]  : 0u;
      u32 c1 = (tid < 8) ? cnt1A[img*NROLE + tid] : 0u;
      u32 n = v & 0x7FFFFFFFu;
      bool ofl = (tid < 8) && (v >> 31);
      u32 incl = n;
      #pragma unroll
      for (int off = 1; off < 8; off <<= 1) { u32 u = __shfl_up(incl, off); if (tid >= off) incl += u; }
      if (tid < 8) { pre[tid] = incl - n; ln[tid] = n; }
      u32 c1s = c1;
      #pragma unroll
      for (int off = 1; off < 8; off <<= 1) c1s += __shfl_xor(c1s, off);
      u64 ob = __ballot(ofl);
      u32 tot = __shfl(incl, 7);
      if (tid == 0) { s_nc = tot; s_c1 = c1s; s_flag = (ob != 0ull) ? 1u : 0u; }
    }
    __syncthreads();

    u32 nc = s_nc;
    const bool fb = (s_flag != 0u) || (nc > CAP) || (nc < TOPK && nc < s_c1);

    if (!fb) {
      // gather 8 segments into lkeys (128 threads per segment)
      const int b = tid >> 7, r = tid & 127;
      const u32 nb = ln[b], pb = pre[b];
      const u64* sg = cand + ((size_t)img*NROLE + b) * SEGCAP;
      for (u32 i = r; i < nb; i += 128) lkeys[pb + i] = sg[i];
    } else {
      // exact fallback re-capture (correctness-only; never taken on this data)
      u32* ph   = (u32*)lkeys;         // 16384 u16-packed bins
      u32* csum = (u32*)skeys;
      for (int t = tid; t < 8192; t += 1024) ph[t] = 0u;
      __syncthreads();
      const float4* cp = ((const float4*)conf) + (size_t)img * (NPRI/2);
      for (int i = tid; i < NPRI/2; i += 1024) {
        float4 v = cp[i];
        if (v.y > 0.01f) { u32 b = __float_as_uint(v.y) >> 17; atomicAdd(&ph[b >> 1], 1u << ((b & 1)*16)); }
        if (v.w > 0.01f) { u32 b = __float_as_uint(v.w) >> 17; atomicAdd(&ph[b >> 1], 1u << ((b & 1)*16)); }
      }
      __syncthreads();
      if (tid < 512) {
        u32 acc = 0;
        #pragma unroll
        for (int w = 0; w < 16; ++w) { u32 v = ph[tid*16 + w]; acc += (v & 0xFFFFu) + (v >> 16); }
        csum[tid] = acc;
      }
      __syncthreads();
      for (int off = 1; off < 512; off <<= 1) {
        u32 v = (tid < 512 && tid + off < 512) ? csum[tid + off] : 0u;
        __syncthreads();
        if (tid < 512) csum[tid] += v;
        __syncthreads();
      }
      if (tid < 512) {
        u32 mine = csum[tid], nxt = (tid < 511) ? csum[tid+1] : 0u;
        if (mine >= TOPK && nxt < TOPK) {
          u32 run = nxt;
          for (int b = 31; b >= 0; --b) {
            u32 bin = tid*32 + b;
            u32 w = ph[bin >> 1];
            run += (bin & 1) ? (w >> 16) : (w & 0xFFFFu);
            if (run >= TOPK) { s_T = bin; break; }
          }
        }
      }
      __syncthreads();
      const u32 T = s_T;
      __syncthreads();
      for (int i = tid; i < NPRI/2; i += 1024) {
        float4 v = cp[i];
        if (v.y > 0.01f) {
          u32 bits = __float_as_uint(v.y);
          if ((bits>>17) >= T) { u32 p = atomicAdd(&s_ctr,1u); if (p < CAP) lkeys[p] = ((u64)bits<<32)|(u64)(0xFFFFFFFFu-(u32)(2*i)); }
        }
        if (v.w > 0.01f) {
          u32 bits = __float_as_uint(v.w);
          if ((bits>>17) >= T) { u32 p = atomicAdd(&s_ctr,1u); if (p < CAP) lkeys[p] = ((u64)bits<<32)|(u64)(0xFFFFFFFFu-(u32)(2*i+1)); }
        }
      }
      __syncthreads();
      nc = s_ctr; if (nc > CAP) nc = CAP;
      if (tid < 512) skeys[tid] = 0ull;  // csum aliased skeys; restore zero pad
    }
    __syncthreads();

    // sort top-512 into skeys (descending); deterministic across blocks
    if (nc <= 512u) {
      if (tid < (int)nc) atomicAdd(&hist[binOf(lkeys[tid])], 1u);
      __syncthreads();
      if (tid < 64) {
        u32 h[8]; u32 s = 0;
        #pragma unroll
        for (int q = 0; q < 8; ++q) { h[q] = hist[tid*8 + q]; s += h[q]; }
        u32 acc = s;
        #pragma unroll
        for (int off = 1; off < 64; off <<= 1) { u32 v = __shfl_down(acc, off); if (tid + off < 64) acc += v; }
        u32 run = acc - s;
        u32 st[8];
        #pragma unroll
        for (int q = 7; q >= 0; --q) { st[q] = run; run += h[q]; }
        #pragma unroll
        for (int q = 0; q < 8; ++q) suffst[tid*8 + q] = st[q];
      }
      __syncthreads();
      u64* tmp = lkeys + 1024;
      if (tid < (int)nc) {
        u64 key = lkeys[tid]; u32 b = binOf(key);
        u32 pos = suffst[b] + atomicAdd(&cnt2[b], 1u);
        tmp[pos] = key;
      }
      __syncthreads();
      if (tid < (int)nc) {
        u64 k = tmp[tid]; u32 b = binOf(k);
        u32 c = hist[b];
        if (c == 1u) skeys[tid] = k;
        else {
          u32 base = suffst[b], r2 = 0;
          for (u32 q = 0; q < c; ++q) r2 += (u32)(tmp[base + q] > k);
          skeys[base + r2] = k;          // within-bin exact rank: deterministic
        }
      }
    } else {
      // generic exact rank-sort (tail-probability / fallback data only)
      u32 ncp = (nc + 3u) & ~3u;
      for (u32 t = tid; t < ncp; t += 1024) if (t >= nc) lkeys[t] = 0ull;
      __syncthreads();
      u64 myk[4]; u32 myr[4];
      #pragma unroll
      for (int r2 = 0; r2 < 4; ++r2) {
        u32 g = (u32)tid + ((u32)r2 << 10);
        myk[r2] = (g < ncp) ? lkeys[g] : 0ull;
        myr[r2] = 0u;
      }
      for (u32 j = 0; j < ncp; ++j) {
        u64 kj = lkeys[j];
        #pragma unroll
        for (int r2 = 0; r2 < 4; ++r2) myr[r2] += (u32)(kj > myk[r2]);
      }
      #pragma unroll
      for (int r2 = 0; r2 < 4; ++r2) {
        u32 g = (u32)tid + ((u32)r2 << 10);
        if (g < nc && myr[r2] < 512u) skeys[myr[r2]] = myk[r2];
      }
    }
    __syncthreads();

    // decode top-200 (+areas)
    if (tid < TOPK) {
      u64 key = skeys[tid];
      float sc = __uint_as_float((u32)(key >> 32));
      float4 bx = make_float4(0.f, 0.f, 0.f, 0.f);
      if (sc > 0.01f) {
        u32 idx = 0xFFFFFFFFu - (u32)(key & 0xFFFFFFFFull);
        float4 l = ((const float4*)loc)[(size_t)img * NPRI + idx];
        float4 p = ((const float4*)priors)[idx];
        float cx = p.x + (l.x * 0.1f) * p.z;
        float cy = p.y + (l.y * 0.1f) * p.w;
        float w  = p.z * expf(l.z * 0.2f);
        float h  = p.w * expf(l.w * 0.2f);
        bx = make_float4(cx - w*0.5f, cy - h*0.5f, cx + w*0.5f, cy + h*0.5f);
      }
      sbox[tid] = bx;
      sarea[tid] = (bx.z - bx.x) * (bx.w - bx.y);
      sscore[tid] = sc;
    }
    __syncthreads();

    // IoU slice: this block owns (slice = role>>1, rowhalf = role&1);
    // thread t<400: row = rowhalf*100 + (t>>2), 16-col quarter q = t&3.
    {
      const int slice = role >> 1;
      const int rowhalf = role & 1;
      if (tid < 400) {
        const int row = rowhalf*100 + (tid >> 2);
        const int q = tid & 3;
        const int j0 = slice*64 + q*16;
        int cnt = TOPK - j0; if (cnt > 16) cnt = 16;
        u32 m = 0;
        if (cnt > 0) {
          float4 bi = sbox[row];
          float ai = sarea[row];
          for (int jj = 0; jj < cnt; ++jj) {
            int j = j0 + jj;
            float4 bj = sbox[j];
            float ltx = fmaxf(bi.x, bj.x), lty = fmaxf(bi.y, bj.y);
            float rbx = fminf(bi.z, bj.z), rby = fminf(bi.w, bj.w);
            float w = fmaxf(rbx - ltx, 0.f), hh = fmaxf(rby - lty, 0.f);
            float inter = w * hh;
            float uni = ai + sarea[j] - inter;
            float iou = inter / uni;
            if (!(iou <= 0.45f)) m |= 1u << jj;   // NaN suppresses
          }
        }
        gmask16[(((size_t)img*NSLICE + slice)*TOPK + row)*4 + q] = (u16)m;
      }
    }
  }
  __threadfence();
  grid.sync();

  // ================= stage C: sweep + emit (role-0 blocks) =================
  if (role != 0) return;
  {
    const u64* gm = (const u64*)gmask16 + (size_t)img * NSLICE * TOPK;
    if (tid < 64) {
      u64 row0[4], row1[4], row2[4], row3[4];
      #pragma unroll
      for (int s = 0; s < 4; ++s) {
        row0[s] = gm[s*TOPK + tid];
        row1[s] = gm[s*TOPK + 64 + tid];
        row2[s] = gm[s*TOPK + 128 + tid];
        row3[s] = (tid < TOPK - 192) ? gm[s*TOPK + 192 + tid] : 0ull;
      }
      bool a0 = sscore[tid] > 0.01f;
      bool a1 = sscore[64 + tid] > 0.01f;
      bool a2 = sscore[128 + tid] > 0.01f;
      bool a3 = (tid < TOPK - 192) ? (sscore[192 + tid] > 0.01f) : false;
      u64 k0 = 0, k1 = 0, k2 = 0, k3 = 0;
      #define SWEEP_SLICE(S, AREG, KREG)                                 \
      {                                                                  \
        u64 aw = __ballot(AREG);                                         \
        while (aw) {                                                     \
          int l = __ffsll((long long)aw) - 1;                            \
          KREG |= 1ull << l;                                             \
          a0 = a0 && !((row0[S] >> l) & 1ull);                           \
          a1 = a1 && !((row1[S] >> l) & 1ull);                           \
          a2 = a2 && !((row2[S] >> l) & 1ull);                           \
          a3 = a3 && !((row3[S] >> l) & 1ull);                           \
          u64 above = (l < 63) ? (~0ull << (l + 1)) : 0ull;              \
          aw = __ballot(AREG) & above;                                   \
        }                                                                \
      }
      SWEEP_SLICE(0, a0, k0)
      SWEEP_SLICE(1, a1, k1)
      SWEEP_SLICE(2, a2, k2)
      SWEEP_SLICE(3, a3, k3)
      #undef SWEEP_SLICE
      if (tid == 0) { sact[0] = k0; sact[1] = k1; sact[2] = k2; sact[3] = k3; }
    }
    __syncthreads();
    if (tid < TOPK) {
      u64 k0 = sact[0], k1 = sact[1], k2 = sact[2], k3 = sact[3];
      int s = tid >> 6, l = tid & 63;
      u64 w = (s == 0) ? k0 : (s == 1) ? k1 : (s == 2) ? k2 : k3;
      if ((w >> l) & 1ull) {
        u32 rank = __popcll(w & ((1ull << l) - 1ull));
        if (s > 0) rank += __popcll(k0);
        if (s > 1) rank += __popcll(k1);
        if (s > 2) rank += __popcll(k2);
        float4 b = sbox[tid];
        float* row = oimg + ((size_t)TOPK + rank) * 5;   // class-1 plane
        row[0] = sscore[tid];
        row[1] = b.x; row[2] = b.y; row[3] = b.z; row[4] = b.w;
      }
    }
  }
}

extern "C" void kernel_launch(void* const* d_in, const int* in_sizes, int n_in,
                              void* d_out, int out_size, void* d_ws, size_t ws_size,
                              hipStream_t stream) {
  const float* loc    = (const float*)d_in[0];
  const float* conf   = (const float*)d_in[1];
  const float* priors = (const float*)d_in[2];
  float* out = (float*)d_out;

  char* w = (char*)d_ws;
  u32* cntA  = (u32*)w;                      w += (size_t)BATCH*NROLE*4;
  u32* cnt1A = (u32*)w;                      w += (size_t)BATCH*NROLE*4;
  u64* cand  = (u64*)w;                      w += (size_t)BATCH*NROLE*SEGCAP*8;
  u16* gmask = (u16*)w;                      // BATCH*NSLICE*TOPK*4 u16

  void* args[] = { (void*)&loc, (void*)&priors, (void*)&conf,
                   (void*)&cntA, (void*)&cnt1A, (void*)&cand,
                   (void*)&gmask, (void*)&out };
  hipLaunchCooperativeKernel((const void*)k_fused, dim3(BATCH*NROLE), dim3(1024),
                             args, 0, stream);
}

// Round 13
// 42.306 us; speedup vs baseline: 5.0471x; 5.0471x over previous
//
#include <hip/hip_runtime.h>

typedef unsigned int u32;
typedef unsigned long long u64;
typedef unsigned short u16;

#define BATCH 32
#define NPRI  200000
#define TOPK  200
#define CAP   4096             // max candidates per image (fallback can fill this)
#define PRE_BITS 0x3F7F8000u   // bits of 0.998046875f; expected ~391 captures/img
#define NBLK  64               // k_cap blocks per image
#define SEGCAP 128             // candidate slots per (img, blk)
#define NSLICE 4

__device__ __forceinline__ u32 binOf(u64 key) {
  u32 bits = (u32)(key >> 32);
  if (bits < PRE_BITS) return 0u;
  u32 b = (bits - PRE_BITS) >> 6;
  return b > 511u ? 511u : b;
}

// ------- pass 1: capture scores >= PRE_BITS into per-block segment; count positives -------
__global__ __launch_bounds__(256) void k_cap(const float* __restrict__ conf,
                                             u32* __restrict__ cntA,
                                             u32* __restrict__ cnt1A,
                                             u64* __restrict__ cand) {
  __shared__ u32 lcnt, lc1;
  if (threadIdx.x == 0) { lcnt = 0u; lc1 = 0u; }
  __syncthreads();
  const int img = blockIdx.y;
  const int blk = blockIdx.x;
  const float4* cp = ((const float4*)conf) + (size_t)img * (NPRI/2);
  u64* cd = cand + ((size_t)img * NBLK + blk) * SEGCAP;
  u32 my001 = 0;
  for (int i = blk*256 + threadIdx.x; i < NPRI/2; i += NBLK*256) {
    float4 v = cp[i];
    if (v.y > 0.01f) {
      ++my001;
      u32 bits = __float_as_uint(v.y);
      if (bits >= PRE_BITS) {
        u32 p = atomicAdd(&lcnt, 1u);
        if (p < SEGCAP) cd[p] = ((u64)bits << 32) | (u64)(0xFFFFFFFFu - (u32)(2*i));
      }
    }
    if (v.w > 0.01f) {
      ++my001;
      u32 bits = __float_as_uint(v.w);
      if (bits >= PRE_BITS) {
        u32 p = atomicAdd(&lcnt, 1u);
        if (p < SEGCAP) cd[p] = ((u64)bits << 32) | (u64)(0xFFFFFFFFu - (u32)(2*i+1));
      }
    }
  }
  if (my001) atomicAdd(&lc1, my001);
  __syncthreads();
  if (threadIdx.x == 0) {
    u32 n = lcnt;
    u32 v = (n > SEGCAP) ? (SEGCAP | 0x80000000u) : n;
    cntA[img * NBLK + blk] = v;
    cnt1A[img * NBLK + blk] = lc1;
  }
}

// ------- pass 2: per (img, slice): gather + overlap-decode + exact-rank scatter + IoU slice -------
// 4 blocks per image redundantly sort/decode (deterministic, runs concurrently on
// different CUs -> no wall-time cost); each computes a 64-col slice of the
// suppression matrix. Slice 0 publishes boxes/scores to ws.
__global__ __launch_bounds__(1024) void k_prep(const float* __restrict__ loc,
                                               const float* __restrict__ priors,
                                               const float* __restrict__ conf,
                                               const u32* __restrict__ cntA,
                                               const u32* __restrict__ cnt1A,
                                               const u64* __restrict__ cand,
                                               float4* __restrict__ gbox,
                                               float* __restrict__ gscore,
                                               u16* __restrict__ gmask16) {
  __shared__ u64    lkeys[CAP];       // 32 KB; fb hist aliases; tmp = lkeys+1024
  __shared__ u64    skeys[512];       // generic/fb path only; fb csum aliases
  __shared__ float4 sbox[TOPK];
  __shared__ float  sarea[TOPK];
  __shared__ float  sscore[TOPK];
  __shared__ u32    suffst[512];
  __shared__ u32    hist[512];
  __shared__ u32    cnt2[512];
  __shared__ u32    pre[NBLK];
  __shared__ u32    ln[NBLK];
  __shared__ u32    s_nc, s_c1, s_flag, s_T, s_ctr;

  const int img = blockIdx.y;
  const int slice = blockIdx.x;
  const int tid = threadIdx.x;
  const u64* gseg = cand + (size_t)img * NBLK * SEGCAP;

  // ---- init + wave0 segment scan ----
  if (tid < 512) { hist[tid] = 0u; cnt2[tid] = 0u; skeys[tid] = 0ull; }
  if (tid < TOPK) {
    sbox[tid] = make_float4(0.f, 0.f, 0.f, 0.f);
    sarea[tid] = 0.f;
    sscore[tid] = 0.f;
  }
  if (tid == 0) { s_T = 0u; s_ctr = 0u; }
  if (tid < 64) {
    u32 v = cntA[img * NBLK + tid];
    u32 n = v & 0x7FFFFFFFu;
    bool ofl = (v >> 31) != 0u;
    u32 c1 = cnt1A[img * NBLK + tid];
    u32 incl = n;
    #pragma unroll
    for (int off = 1; off < 64; off <<= 1) { u32 u = __shfl_up(incl, off); if (tid >= off) incl += u; }
    pre[tid] = incl - n;
    ln[tid] = n;
    u32 tot = __shfl(incl, 63);
    u32 c1s = c1;
    #pragma unroll
    for (int off = 1; off < 64; off <<= 1) c1s += __shfl_xor(c1s, off);
    u64 ob = __ballot(ofl);
    if (tid == 0) { s_nc = tot; s_c1 = c1s; s_flag = (ob != 0ull) ? 1u : 0u; }
  }
  __syncthreads();

  u32 nc = s_nc;
  const bool fb = (s_flag != 0u) || (nc > CAP) || (nc < TOPK && nc < s_c1);
  bool generic = fb;                    // generic path also taken if nc > 512

  if (!fb) {
    // ---- gather 64 segments into lkeys (16 threads per segment) ----
    const int b = tid >> 4, r = tid & 15;
    const u32 nb = ln[b], pb = pre[b];
    const u64* sg = gseg + (size_t)b * SEGCAP;
    for (u32 i = r; i < nb; i += 16) lkeys[pb + i] = sg[i];
    if (nc > 512u) generic = true;
  } else {
    // ---- exact fallback re-capture (correctness-only; never taken on this data) ----
    u32* ph   = (u32*)lkeys;            // 8192 words, 16384 packed u16 bins
    u32* csum = (u32*)skeys;            // 512 chunk sums
    for (int t = tid; t < 8192; t += 1024) ph[t] = 0u;
    __syncthreads();
    const float4* cp = ((const float4*)conf) + (size_t)img * (NPRI/2);
    for (int i = tid; i < NPRI/2; i += 1024) {
      float4 v = cp[i];
      if (v.y > 0.01f) { u32 b = __float_as_uint(v.y) >> 17; atomicAdd(&ph[b >> 1], 1u << ((b & 1)*16)); }
      if (v.w > 0.01f) { u32 b = __float_as_uint(v.w) >> 17; atomicAdd(&ph[b >> 1], 1u << ((b & 1)*16)); }
    }
    __syncthreads();
    if (tid < 512) {
      u32 acc = 0;
      #pragma unroll
      for (int w = 0; w < 16; ++w) { u32 v = ph[tid*16 + w]; acc += (v & 0xFFFFu) + (v >> 16); }
      csum[tid] = acc;
    }
    __syncthreads();
    for (int off = 1; off < 512; off <<= 1) {
      u32 v = (tid < 512 && tid + off < 512) ? csum[tid + off] : 0u;
      __syncthreads();
      if (tid < 512) csum[tid] += v;
      __syncthreads();
    }
    if (tid < 512) {
      u32 mine = csum[tid], nxt = (tid < 511) ? csum[tid+1] : 0u;
      if (mine >= TOPK && nxt < TOPK) {
        u32 run = nxt;
        for (int b = 31; b >= 0; --b) {
          u32 bin = tid*32 + b;
          u32 w = ph[bin >> 1];
          run += (bin & 1) ? (w >> 16) : (w & 0xFFFFu);
          if (run >= TOPK) { s_T = bin; break; }
        }
      }
    }
    __syncthreads();
    const u32 T = s_T;
    __syncthreads();
    for (int i = tid; i < NPRI/2; i += 1024) {
      float4 v = cp[i];
      if (v.y > 0.01f) {
        u32 bits = __float_as_uint(v.y);
        if ((bits>>17) >= T) { u32 p = atomicAdd(&s_ctr,1u); if (p < CAP) lkeys[p] = ((u64)bits<<32)|(u64)(0xFFFFFFFFu-(u32)(2*i)); }
      }
      if (v.w > 0.01f) {
        u32 bits = __float_as_uint(v.w);
        if ((bits>>17) >= T) { u32 p = atomicAdd(&s_ctr,1u); if (p < CAP) lkeys[p] = ((u64)bits<<32)|(u64)(0xFFFFFFFFu-(u32)(2*i+1)); }
      }
    }
    __syncthreads();
    nc = s_ctr; if (nc > CAP) nc = CAP;
    if (tid < 512) skeys[tid] = 0ull;   // csum aliased skeys; restore zero pad
  }
  __syncthreads();

  if (!generic) {
    // ---- hot path: overlap decode with exact-rank selection (nc <= 512) ----
    u64 mykey = 0; u32 mybin = 0;
    float4 mybox = make_float4(0.f, 0.f, 0.f, 0.f);
    float mysc = 0.f;
    if (tid < (int)nc) {
      mykey = lkeys[tid];
      mysc = __uint_as_float((u32)(mykey >> 32));
      mybin = binOf(mykey);
      atomicAdd(&hist[mybin], 1u);
      // decode now: global loads issue here, consumed 3 phases later
      u32 idx = 0xFFFFFFFFu - (u32)(mykey & 0xFFFFFFFFull);
      float4 l = ((const float4*)loc)[(size_t)img * NPRI + idx];
      float4 p = ((const float4*)priors)[idx];
      float cx = p.x + (l.x * 0.1f) * p.z;
      float cy = p.y + (l.y * 0.1f) * p.w;
      float w  = p.z * expf(l.z * 0.2f);
      float h  = p.w * expf(l.w * 0.2f);
      mybox = make_float4(cx - w*0.5f, cy - h*0.5f, cx + w*0.5f, cy + h*0.5f);
    }
    __syncthreads();
    // wave0: suffix starts over 512 bins (8 bins/lane)
    if (tid < 64) {
      u32 h[8]; u32 s = 0;
      #pragma unroll
      for (int q = 0; q < 8; ++q) { h[q] = hist[tid*8 + q]; s += h[q]; }
      u32 acc = s;
      #pragma unroll
      for (int off = 1; off < 64; off <<= 1) { u32 v = __shfl_down(acc, off); if (tid + off < 64) acc += v; }
      u32 run = acc - s;                 // keys in higher lanes (higher bins)
      u32 st[8];
      #pragma unroll
      for (int q = 7; q >= 0; --q) { st[q] = run; run += h[q]; }
      #pragma unroll
      for (int q = 0; q < 8; ++q) suffst[tid*8 + q] = st[q];
    }
    __syncthreads();
    u64* tmp = lkeys + 1024;
    if (tid < (int)nc) tmp[suffst[mybin] + atomicAdd(&cnt2[mybin], 1u)] = mykey;
    __syncthreads();
    if (tid < (int)nc) {
      u32 c = hist[mybin], base = suffst[mybin];
      u32 pos = base;
      if (c > 1u) {
        u32 r2 = 0;
        for (u32 q = 0; q < c; ++q) r2 += (u32)(tmp[base + q] > mykey);
        pos = base + r2;                 // exact rank: deterministic
      }
      if (pos < TOPK) {
        sbox[pos] = mybox;
        sarea[pos] = (mybox.z - mybox.x) * (mybox.w - mybox.y);
        sscore[pos] = mysc;
      }
    }
  } else {
    // ---- generic exact rank-sort + decode (fallback data only) ----
    u32 ncp = (nc + 3u) & ~3u;
    for (u32 t = tid; t < ncp; t += 1024) if (t >= nc) lkeys[t] = 0ull;
    __syncthreads();
    u64 myk[4]; u32 myr[4];
    #pragma unroll
    for (int r2 = 0; r2 < 4; ++r2) {
      u32 g = (u32)tid + ((u32)r2 << 10);
      myk[r2] = (g < ncp) ? lkeys[g] : 0ull;
      myr[r2] = 0u;
    }
    for (u32 j = 0; j < ncp; ++j) {
      u64 kj = lkeys[j];
      #pragma unroll
      for (int r2 = 0; r2 < 4; ++r2) myr[r2] += (u32)(kj > myk[r2]);
    }
    #pragma unroll
    for (int r2 = 0; r2 < 4; ++r2) {
      u32 g = (u32)tid + ((u32)r2 << 10);
      if (g < nc && myr[r2] < 512u) skeys[myr[r2]] = myk[r2];
    }
    __syncthreads();
    if (tid < TOPK) {
      u64 key = skeys[tid];
      float sc = __uint_as_float((u32)(key >> 32));
      float4 bx = make_float4(0.f, 0.f, 0.f, 0.f);
      if (sc > 0.01f) {
        u32 idx = 0xFFFFFFFFu - (u32)(key & 0xFFFFFFFFull);
        float4 l = ((const float4*)loc)[(size_t)img * NPRI + idx];
        float4 p = ((const float4*)priors)[idx];
        float cx = p.x + (l.x * 0.1f) * p.z;
        float cy = p.y + (l.y * 0.1f) * p.w;
        float w  = p.z * expf(l.z * 0.2f);
        float h  = p.w * expf(l.w * 0.2f);
        bx = make_float4(cx - w*0.5f, cy - h*0.5f, cx + w*0.5f, cy + h*0.5f);
      }
      sbox[tid] = bx;
      sarea[tid] = (bx.z - bx.x) * (bx.w - bx.y);
      sscore[tid] = sc;
    }
  }
  __syncthreads();

  // ---- slice 0 publishes boxes/scores ----
  if (slice == 0 && tid < TOPK) {
    gbox[(size_t)img * TOPK + tid] = sbox[tid];
    gscore[(size_t)img * TOPK + tid] = sscore[tid];
  }

  // ---- IoU slice: row = tid>>2 (0..199), 16-col quarter q = tid&3 ----
  if (tid < 4*TOPK) {
    const int row = tid >> 2;
    const int q = tid & 3;
    const int j0 = slice*64 + q*16;
    int cnt = TOPK - j0; if (cnt > 16) cnt = 16;
    u32 m = 0;
    if (cnt > 0) {
      float4 bi = sbox[row];
      float ai = sarea[row];
      for (int jj = 0; jj < cnt; ++jj) {
        int j = j0 + jj;
        float4 bj = sbox[j];
        float ltx = fmaxf(bi.x, bj.x), lty = fmaxf(bi.y, bj.y);
        float rbx = fminf(bi.z, bj.z), rby = fminf(bi.w, bj.w);
        float w = fmaxf(rbx - ltx, 0.f), hh = fmaxf(rby - lty, 0.f);
        float inter = w * hh;
        float uni = ai + sarea[j] - inter;
        float iou = inter / uni;
        if (!(iou <= 0.45f)) m |= 1u << jj;   // NaN suppresses
      }
    }
    gmask16[(((size_t)img*NSLICE + slice)*TOPK + row)*4 + q] = (u16)m;
  }
}

// ------- pass 3: greedy sweep (kept-bit skipping) + emit + zero slab -------
__global__ __launch_bounds__(256) void k_sweep(const float4* __restrict__ gbox,
                                               const float* __restrict__ gscore,
                                               const u64* __restrict__ gmask,
                                               float* __restrict__ out) {
  __shared__ float4 sbx[TOPK];
  __shared__ float  ssc[TOPK];
  __shared__ u64    sact[4];
  const int img = blockIdx.x;
  const int tid = threadIdx.x;
  float* oimg = out + (size_t)img * 2 * TOPK * 5;

  for (int i = tid; i < 2*TOPK*5; i += 256) oimg[i] = 0.0f;
  if (tid < TOPK) {
    sbx[tid] = gbox[(size_t)img * TOPK + tid];
    ssc[tid] = gscore[(size_t)img * TOPK + tid];
  }
  __syncthreads();

  if (tid < 64) {
    const u64* gm = gmask + (size_t)img * NSLICE * TOPK;
    u64 row0[4], row1[4], row2[4], row3[4];
    #pragma unroll
    for (int s = 0; s < 4; ++s) {
      row0[s] = gm[s*TOPK + tid];
      row1[s] = gm[s*TOPK + 64 + tid];
      row2[s] = gm[s*TOPK + 128 + tid];
      row3[s] = (tid < TOPK - 192) ? gm[s*TOPK + 192 + tid] : 0ull;
    }
    bool a0 = ssc[tid] > 0.01f;
    bool a1 = ssc[64 + tid] > 0.01f;
    bool a2 = ssc[128 + tid] > 0.01f;
    bool a3 = (tid < TOPK - 192) ? (ssc[192 + tid] > 0.01f) : false;
    u64 k0 = 0, k1 = 0, k2 = 0, k3 = 0;

    #define SWEEP_SLICE(S, AREG, KREG)                                   \
    {                                                                    \
      u64 aw = __ballot(AREG);                                           \
      while (aw) {                                                       \
        int l = __ffsll((long long)aw) - 1;                              \
        KREG |= 1ull << l;                                               \
        a0 = a0 && !((row0[S] >> l) & 1ull);                             \
        a1 = a1 && !((row1[S] >> l) & 1ull);                             \
        a2 = a2 && !((row2[S] >> l) & 1ull);                             \
        a3 = a3 && !((row3[S] >> l) & 1ull);                             \
        u64 above = (l < 63) ? (~0ull << (l + 1)) : 0ull;                \
        aw = __ballot(AREG) & above;                                     \
      }                                                                  \
    }
    SWEEP_SLICE(0, a0, k0)
    SWEEP_SLICE(1, a1, k1)
    SWEEP_SLICE(2, a2, k2)
    SWEEP_SLICE(3, a3, k3)
    #undef SWEEP_SLICE

    if (tid == 0) { sact[0] = k0; sact[1] = k1; sact[2] = k2; sact[3] = k3; }
  }
  __syncthreads();

  if (tid < TOPK) {
    u64 k0 = sact[0], k1 = sact[1], k2 = sact[2], k3 = sact[3];
    int s = tid >> 6, l = tid & 63;
    u64 w = (s == 0) ? k0 : (s == 1) ? k1 : (s == 2) ? k2 : k3;
    if ((w >> l) & 1ull) {
      u32 rank = __popcll(w & ((1ull << l) - 1ull));
      if (s > 0) rank += __popcll(k0);
      if (s > 1) rank += __popcll(k1);
      if (s > 2) rank += __popcll(k2);
      float4 b = sbx[tid];
      float* row = oimg + ((size_t)TOPK + rank) * 5;   // class-1 plane
      row[0] = ssc[tid];
      row[1] = b.x; row[2] = b.y; row[3] = b.z; row[4] = b.w;
    }
  }
}

extern "C" void kernel_launch(void* const* d_in, const int* in_sizes, int n_in,
                              void* d_out, int out_size, void* d_ws, size_t ws_size,
                              hipStream_t stream) {
  const float* loc    = (const float*)d_in[0];
  const float* conf   = (const float*)d_in[1];
  const float* priors = (const float*)d_in[2];
  float* out = (float*)d_out;

  char* w = (char*)d_ws;
  u32* cntA  = (u32*)w;                                  w += (size_t)BATCH*NBLK*4;
  u32* cnt1A = (u32*)w;                                  w += (size_t)BATCH*NBLK*4;
  u64* cand  = (u64*)w;                                  w += (size_t)BATCH*NBLK*SEGCAP*8;
  float4* gbox = (float4*)w;                             w += (size_t)BATCH*TOPK*16;
  float* gscore = (float*)w;                             w += (size_t)BATCH*TOPK*4;
  u64* gmask = (u64*)w;                                  // BATCH*NSLICE*TOPK u64

  k_cap  <<<dim3(NBLK, BATCH), 256, 0, stream>>>(conf, cntA, cnt1A, cand);
  k_prep <<<dim3(NSLICE, BATCH), 1024, 0, stream>>>(loc, priors, conf, cntA, cnt1A, cand,
                                                    gbox, gscore, (u16*)gmask);
  k_sweep<<<BATCH, 256, 0, stream>>>(gbox, gscore, gmask, out);
}

// Round 16
// 42.250 us; speedup vs baseline: 5.0538x; 1.0013x over previous
//
#include <hip/hip_runtime.h>

typedef unsigned int u32;
typedef unsigned long long u64;
typedef unsigned short u16;

#define BATCH 32
#define NPRI  200000
#define TOPK  200
#define CAP   4096             // max candidates per image (fallback can fill this)
#define PRE_BITS 0x3F7F8000u   // bits of 0.998046875f; expected ~391 captures/img
#define NBLK  64               // k_cap blocks per image
#define SEGCAP 128             // candidate slots per (img, blk)
#define NSLICE 4

__device__ __forceinline__ u32 binOf(u64 key) {
  u32 bits = (u32)(key >> 32);
  if (bits < PRE_BITS) return 0u;
  u32 b = (bits - PRE_BITS) >> 6;
  return b > 511u ? 511u : b;
}

// ------- pass 1: capture scores >= PRE_BITS into per-block segment; count positives -------
__global__ __launch_bounds__(256) void k_cap(const float* __restrict__ conf,
                                             u32* __restrict__ cntA,
                                             u32* __restrict__ cnt1A,
                                             u64* __restrict__ cand) {
  __shared__ u32 lcnt, lc1;
  if (threadIdx.x == 0) { lcnt = 0u; lc1 = 0u; }
  __syncthreads();
  const int img = blockIdx.y;
  const int blk = blockIdx.x;
  const float4* cp = ((const float4*)conf) + (size_t)img * (NPRI/2);
  u64* cd = cand + ((size_t)img * NBLK + blk) * SEGCAP;
  u32 my001 = 0;
  for (int i = blk*256 + threadIdx.x; i < NPRI/2; i += NBLK*256) {
    float4 v = cp[i];
    if (v.y > 0.01f) {
      ++my001;
      u32 bits = __float_as_uint(v.y);
      if (bits >= PRE_BITS) {
        u32 p = atomicAdd(&lcnt, 1u);
        if (p < SEGCAP) cd[p] = ((u64)bits << 32) | (u64)(0xFFFFFFFFu - (u32)(2*i));
      }
    }
    if (v.w > 0.01f) {
      ++my001;
      u32 bits = __float_as_uint(v.w);
      if (bits >= PRE_BITS) {
        u32 p = atomicAdd(&lcnt, 1u);
        if (p < SEGCAP) cd[p] = ((u64)bits << 32) | (u64)(0xFFFFFFFFu - (u32)(2*i+1));
      }
    }
  }
  if (my001) atomicAdd(&lc1, my001);
  __syncthreads();
  if (threadIdx.x == 0) {
    u32 n = lcnt;
    u32 v = (n > SEGCAP) ? (SEGCAP | 0x80000000u) : n;
    cntA[img * NBLK + blk] = v;
    cnt1A[img * NBLK + blk] = lc1;
  }
}

// ------- pass 2: per (img, slice): gather + overlap-decode + exact-rank scatter + IoU slice -------
// 4 blocks per image redundantly sort/decode (deterministic, runs concurrently on
// different CUs -> no wall-time cost); each computes a 64-col slice of the
// suppression matrix. Slice 0 publishes boxes/scores to ws.
__global__ __launch_bounds__(1024) void k_prep(const float* __restrict__ loc,
                                               const float* __restrict__ priors,
                                               const float* __restrict__ conf,
                                               const u32* __restrict__ cntA,
                                               const u32* __restrict__ cnt1A,
                                               const u64* __restrict__ cand,
                                               float4* __restrict__ gbox,
                                               float* __restrict__ gscore,
                                               u16* __restrict__ gmask16) {
  __shared__ u64    lkeys[CAP];       // 32 KB; fb hist aliases; tmp = lkeys+1024
  __shared__ u64    skeys[512];       // generic/fb path only; fb csum aliases
  __shared__ float4 sbox[TOPK];
  __shared__ float  sarea[TOPK];
  __shared__ float  sscore[TOPK];
  __shared__ u32    suffst[512];
  __shared__ u32    hist[512];
  __shared__ u32    cnt2[512];
  __shared__ u32    pre[NBLK];
  __shared__ u32    ln[NBLK];
  __shared__ u32    s_nc, s_c1, s_flag, s_T, s_ctr;

  const int img = blockIdx.y;
  const int slice = blockIdx.x;
  const int tid = threadIdx.x;
  const u64* gseg = cand + (size_t)img * NBLK * SEGCAP;

  // ---- init + wave0 segment scan ----
  if (tid < 512) { hist[tid] = 0u; cnt2[tid] = 0u; skeys[tid] = 0ull; }
  if (tid < TOPK) {
    sbox[tid] = make_float4(0.f, 0.f, 0.f, 0.f);
    sarea[tid] = 0.f;
    sscore[tid] = 0.f;
  }
  if (tid == 0) { s_T = 0u; s_ctr = 0u; }
  if (tid < 64) {
    u32 v = cntA[img * NBLK + tid];
    u32 n = v & 0x7FFFFFFFu;
    bool ofl = (v >> 31) != 0u;
    u32 c1 = cnt1A[img * NBLK + tid];
    u32 incl = n;
    #pragma unroll
    for (int off = 1; off < 64; off <<= 1) { u32 u = __shfl_up(incl, off); if (tid >= off) incl += u; }
    pre[tid] = incl - n;
    ln[tid] = n;
    u32 tot = __shfl(incl, 63);
    u32 c1s = c1;
    #pragma unroll
    for (int off = 1; off < 64; off <<= 1) c1s += __shfl_xor(c1s, off);
    u64 ob = __ballot(ofl);
    if (tid == 0) { s_nc = tot; s_c1 = c1s; s_flag = (ob != 0ull) ? 1u : 0u; }
  }
  __syncthreads();

  u32 nc = s_nc;
  const bool fb = (s_flag != 0u) || (nc > CAP) || (nc < TOPK && nc < s_c1);
  bool generic = fb;                    // generic path also taken if nc > 512

  if (!fb) {
    // ---- gather 64 segments into lkeys (16 threads per segment) ----
    const int b = tid >> 4, r = tid & 15;
    const u32 nb = ln[b], pb = pre[b];
    const u64* sg = gseg + (size_t)b * SEGCAP;
    for (u32 i = r; i < nb; i += 16) lkeys[pb + i] = sg[i];
    if (nc > 512u) generic = true;
  } else {
    // ---- exact fallback re-capture (correctness-only; never taken on this data) ----
    u32* ph   = (u32*)lkeys;            // 8192 words, 16384 packed u16 bins
    u32* csum = (u32*)skeys;            // 512 chunk sums
    for (int t = tid; t < 8192; t += 1024) ph[t] = 0u;
    __syncthreads();
    const float4* cp = ((const float4*)conf) + (size_t)img * (NPRI/2);
    for (int i = tid; i < NPRI/2; i += 1024) {
      float4 v = cp[i];
      if (v.y > 0.01f) { u32 b = __float_as_uint(v.y) >> 17; atomicAdd(&ph[b >> 1], 1u << ((b & 1)*16)); }
      if (v.w > 0.01f) { u32 b = __float_as_uint(v.w) >> 17; atomicAdd(&ph[b >> 1], 1u << ((b & 1)*16)); }
    }
    __syncthreads();
    if (tid < 512) {
      u32 acc = 0;
      #pragma unroll
      for (int w = 0; w < 16; ++w) { u32 v = ph[tid*16 + w]; acc += (v & 0xFFFFu) + (v >> 16); }
      csum[tid] = acc;
    }
    __syncthreads();
    for (int off = 1; off < 512; off <<= 1) {
      u32 v = (tid < 512 && tid + off < 512) ? csum[tid + off] : 0u;
      __syncthreads();
      if (tid < 512) csum[tid] += v;
      __syncthreads();
    }
    if (tid < 512) {
      u32 mine = csum[tid], nxt = (tid < 511) ? csum[tid+1] : 0u;
      if (mine >= TOPK && nxt < TOPK) {
        u32 run = nxt;
        for (int b = 31; b >= 0; --b) {
          u32 bin = tid*32 + b;
          u32 w = ph[bin >> 1];
          run += (bin & 1) ? (w >> 16) : (w & 0xFFFFu);
          if (run >= TOPK) { s_T = bin; break; }
        }
      }
    }
    __syncthreads();
    const u32 T = s_T;
    __syncthreads();
    for (int i = tid; i < NPRI/2; i += 1024) {
      float4 v = cp[i];
      if (v.y > 0.01f) {
        u32 bits = __float_as_uint(v.y);
        if ((bits>>17) >= T) { u32 p = atomicAdd(&s_ctr,1u); if (p < CAP) lkeys[p] = ((u64)bits<<32)|(u64)(0xFFFFFFFFu-(u32)(2*i)); }
      }
      if (v.w > 0.01f) {
        u32 bits = __float_as_uint(v.w);
        if ((bits>>17) >= T) { u32 p = atomicAdd(&s_ctr,1u); if (p < CAP) lkeys[p] = ((u64)bits<<32)|(u64)(0xFFFFFFFFu-(u32)(2*i+1)); }
      }
    }
    __syncthreads();
    nc = s_ctr; if (nc > CAP) nc = CAP;
    if (tid < 512) skeys[tid] = 0ull;   // csum aliased skeys; restore zero pad
  }
  __syncthreads();

  if (!generic) {
    // ---- hot path: overlap decode with exact-rank selection (nc <= 512) ----
    u64 mykey = 0; u32 mybin = 0;
    float4 mybox = make_float4(0.f, 0.f, 0.f, 0.f);
    float mysc = 0.f;
    if (tid < (int)nc) {
      mykey = lkeys[tid];
      mysc = __uint_as_float((u32)(mykey >> 32));
      mybin = binOf(mykey);
      atomicAdd(&hist[mybin], 1u);
      // decode now: global loads issue here, consumed 3 phases later
      u32 idx = 0xFFFFFFFFu - (u32)(mykey & 0xFFFFFFFFull);
      float4 l = ((const float4*)loc)[(size_t)img * NPRI + idx];
      float4 p = ((const float4*)priors)[idx];
      float cx = p.x + (l.x * 0.1f) * p.z;
      float cy = p.y + (l.y * 0.1f) * p.w;
      float w  = p.z * expf(l.z * 0.2f);
      float h  = p.w * expf(l.w * 0.2f);
      mybox = make_float4(cx - w*0.5f, cy - h*0.5f, cx + w*0.5f, cy + h*0.5f);
    }
    __syncthreads();
    // wave0: suffix starts over 512 bins (8 bins/lane)
    if (tid < 64) {
      u32 h[8]; u32 s = 0;
      #pragma unroll
      for (int q = 0; q < 8; ++q) { h[q] = hist[tid*8 + q]; s += h[q]; }
      u32 acc = s;
      #pragma unroll
      for (int off = 1; off < 64; off <<= 1) { u32 v = __shfl_down(acc, off); if (tid + off < 64) acc += v; }
      u32 run = acc - s;                 // keys in higher lanes (higher bins)
      u32 st[8];
      #pragma unroll
      for (int q = 7; q >= 0; --q) { st[q] = run; run += h[q]; }
      #pragma unroll
      for (int q = 0; q < 8; ++q) suffst[tid*8 + q] = st[q];
    }
    __syncthreads();
    u64* tmp = lkeys + 1024;
    if (tid < (int)nc) tmp[suffst[mybin] + atomicAdd(&cnt2[mybin], 1u)] = mykey;
    __syncthreads();
    if (tid < (int)nc) {
      u32 c = hist[mybin], base = suffst[mybin];
      u32 pos = base;
      if (c > 1u) {
        u32 r2 = 0;
        for (u32 q = 0; q < c; ++q) r2 += (u32)(tmp[base + q] > mykey);
        pos = base + r2;                 // exact rank: deterministic
      }
      if (pos < TOPK) {
        sbox[pos] = mybox;
        sarea[pos] = (mybox.z - mybox.x) * (mybox.w - mybox.y);
        sscore[pos] = mysc;
      }
    }
  } else {
    // ---- generic exact rank-sort + decode (fallback data only) ----
    u32 ncp = (nc + 3u) & ~3u;
    for (u32 t = tid; t < ncp; t += 1024) if (t >= nc) lkeys[t] = 0ull;
    __syncthreads();
    u64 myk[4]; u32 myr[4];
    #pragma unroll
    for (int r2 = 0; r2 < 4; ++r2) {
      u32 g = (u32)tid + ((u32)r2 << 10);
      myk[r2] = (g < ncp) ? lkeys[g] : 0ull;
      myr[r2] = 0u;
    }
    for (u32 j = 0; j < ncp; ++j) {
      u64 kj = lkeys[j];
      #pragma unroll
      for (int r2 = 0; r2 < 4; ++r2) myr[r2] += (u32)(kj > myk[r2]);
    }
    #pragma unroll
    for (int r2 = 0; r2 < 4; ++r2) {
      u32 g = (u32)tid + ((u32)r2 << 10);
      if (g < nc && myr[r2] < 512u) skeys[myr[r2]] = myk[r2];
    }
    __syncthreads();
    if (tid < TOPK) {
      u64 key = skeys[tid];
      float sc = __uint_as_float((u32)(key >> 32));
      float4 bx = make_float4(0.f, 0.f, 0.f, 0.f);
      if (sc > 0.01f) {
        u32 idx = 0xFFFFFFFFu - (u32)(key & 0xFFFFFFFFull);
        float4 l = ((const float4*)loc)[(size_t)img * NPRI + idx];
        float4 p = ((const float4*)priors)[idx];
        float cx = p.x + (l.x * 0.1f) * p.z;
        float cy = p.y + (l.y * 0.1f) * p.w;
        float w  = p.z * expf(l.z * 0.2f);
        float h  = p.w * expf(l.w * 0.2f);
        bx = make_float4(cx - w*0.5f, cy - h*0.5f, cx + w*0.5f, cy + h*0.5f);
      }
      sbox[tid] = bx;
      sarea[tid] = (bx.z - bx.x) * (bx.w - bx.y);
      sscore[tid] = sc;
    }
  }
  __syncthreads();

  // ---- slice 0 publishes boxes/scores ----
  if (slice == 0 && tid < TOPK) {
    gbox[(size_t)img * TOPK + tid] = sbox[tid];
    gscore[(size_t)img * TOPK + tid] = sscore[tid];
  }

  // ---- IoU slice: row = tid>>2 (0..199), 16-col quarter q = tid&3 ----
  if (tid < 4*TOPK) {
    const int row = tid >> 2;
    const int q = tid & 3;
    const int j0 = slice*64 + q*16;
    int cnt = TOPK - j0; if (cnt > 16) cnt = 16;
    u32 m = 0;
    if (cnt > 0) {
      float4 bi = sbox[row];
      float ai = sarea[row];
      for (int jj = 0; jj < cnt; ++jj) {
        int j = j0 + jj;
        float4 bj = sbox[j];
        float ltx = fmaxf(bi.x, bj.x), lty = fmaxf(bi.y, bj.y);
        float rbx = fminf(bi.z, bj.z), rby = fminf(bi.w, bj.w);
        float w = fmaxf(rbx - ltx, 0.f), hh = fmaxf(rby - lty, 0.f);
        float inter = w * hh;
        float uni = ai + sarea[j] - inter;
        float iou = inter / uni;
        if (!(iou <= 0.45f)) m |= 1u << jj;   // NaN suppresses
      }
    }
    gmask16[(((size_t)img*NSLICE + slice)*TOPK + row)*4 + q] = (u16)m;
  }
}

// ------- pass 3: greedy sweep (kept-bit skipping) + emit + zero slab -------
__global__ __launch_bounds__(256) void k_sweep(const float4* __restrict__ gbox,
                                               const float* __restrict__ gscore,
                                               const u64* __restrict__ gmask,
                                               float* __restrict__ out) {
  __shared__ float4 sbx[TOPK];
  __shared__ float  ssc[TOPK];
  __shared__ u64    sact[4];
  const int img = blockIdx.x;
  const int tid = threadIdx.x;
  float* oimg = out + (size_t)img * 2 * TOPK * 5;

  for (int i = tid; i < 2*TOPK*5; i += 256) oimg[i] = 0.0f;
  if (tid < TOPK) {
    sbx[tid] = gbox[(size_t)img * TOPK + tid];
    ssc[tid] = gscore[(size_t)img * TOPK + tid];
  }
  __syncthreads();

  if (tid < 64) {
    const u64* gm = gmask + (size_t)img * NSLICE * TOPK;
    u64 row0[4], row1[4], row2[4], row3[4];
    #pragma unroll
    for (int s = 0; s < 4; ++s) {
      row0[s] = gm[s*TOPK + tid];
      row1[s] = gm[s*TOPK + 64 + tid];
      row2[s] = gm[s*TOPK + 128 + tid];
      row3[s] = (tid < TOPK - 192) ? gm[s*TOPK + 192 + tid] : 0ull;
    }
    bool a0 = ssc[tid] > 0.01f;
    bool a1 = ssc[64 + tid] > 0.01f;
    bool a2 = ssc[128 + tid] > 0.01f;
    bool a3 = (tid < TOPK - 192) ? (ssc[192 + tid] > 0.01f) : false;
    u64 k0 = 0, k1 = 0, k2 = 0, k3 = 0;

    #define SWEEP_SLICE(S, AREG, KREG)                                   \
    {                                                                    \
      u64 aw = __ballot(AREG);                                           \
      while (aw) {                                                       \
        int l = __ffsll((long long)aw) - 1;                              \
        KREG |= 1ull << l;                                               \
        a0 = a0 && !((row0[S] >> l) & 1ull);                             \
        a1 = a1 && !((row1[S] >> l) & 1ull);                             \
        a2 = a2 && !((row2[S] >> l) & 1ull);                             \
        a3 = a3 && !((row3[S] >> l) & 1ull);                             \
        u64 above = (l < 63) ? (~0ull << (l + 1)) : 0ull;                \
        aw = __ballot(AREG) & above;                                     \
      }                                                                  \
    }
    SWEEP_SLICE(0, a0, k0)
    SWEEP_SLICE(1, a1, k1)
    SWEEP_SLICE(2, a2, k2)
    SWEEP_SLICE(3, a3, k3)
    #undef SWEEP_SLICE

    if (tid == 0) { sact[0] = k0; sact[1] = k1; sact[2] = k2; sact[3] = k3; }
  }
  __syncthreads();

  if (tid < TOPK) {
    u64 k0 = sact[0], k1 = sact[1], k2 = sact[2], k3 = sact[3];
    int s = tid >> 6, l = tid & 63;
    u64 w = (s == 0) ? k0 : (s == 1) ? k1 : (s == 2) ? k2 : k3;
    if ((w >> l) & 1ull) {
      u32 rank = __popcll(w & ((1ull << l) - 1ull));
      if (s > 0) rank += __popcll(k0);
      if (s > 1) rank += __popcll(k1);
      if (s > 2) rank += __popcll(k2);
      float4 b = sbx[tid];
      float* row = oimg + ((size_t)TOPK + rank) * 5;   // class-1 plane
      row[0] = ssc[tid];
      row[1] = b.x; row[2] = b.y; row[3] = b.z; row[4] = b.w;
    }
  }
}

extern "C" void kernel_launch(void* const* d_in, const int* in_sizes, int n_in,
                              void* d_out, int out_size, void* d_ws, size_t ws_size,
                              hipStream_t stream) {
  const float* loc    = (const float*)d_in[0];
  const float* conf   = (const float*)d_in[1];
  const float* priors = (const float*)d_in[2];
  float* out = (float*)d_out;

  char* w = (char*)d_ws;
  u32* cntA  = (u32*)w;                                  w += (size_t)BATCH*NBLK*4;
  u32* cnt1A = (u32*)w;                                  w += (size_t)BATCH*NBLK*4;
  u64* cand  = (u64*)w;                                  w += (size_t)BATCH*NBLK*SEGCAP*8;
  float4* gbox = (float4*)w;                             w += (size_t)BATCH*TOPK*16;
  float* gscore = (float*)w;                             w += (size_t)BATCH*TOPK*4;
  u64* gmask = (u64*)w;                                  // BATCH*NSLICE*TOPK u64

  k_cap  <<<dim3(NBLK, BATCH), 256, 0, stream>>>(conf, cntA, cnt1A, cand);
  k_prep <<<dim3(NSLICE, BATCH), 1024, 0, stream>>>(loc, priors, conf, cntA, cnt1A, cand,
                                                    gbox, gscore, (u16*)gmask);
  k_sweep<<<BATCH, 256, 0, stream>>>(gbox, gscore, gmask, out);
}